// Round 1
// baseline (841.091 us; speedup 1.0000x reference)
//
#include <hip/hip_runtime.h>
#include <hip/hip_bf16.h>

// SoftmaxPooling on MI355X (gfx950).
//   scores = tanh(h @ W1 + b1) @ w2 (+b2, cancels in softmax)
//   per-track (10 consecutive hits) softmax -> weights
//   pooled[track] = sum_i w_i * h[i]
//
// Fused single kernel:
//   Phase A: stage W1^T as bf16 into LDS (padded stride 264 -> conflict-free b128 B-frag reads)
//   Phase B: bf16 MFMA 16x16x32 GEMM for scores; each wave holds 3-4 row-strips of A in
//            registers so one LDS B-fragment read feeds 3-4 MFMAs.
//   Phase C: per-track softmax in LDS
//   Phase D: weighted pooling, h re-read from global (accepted cost this round)
//
// Block = 512 threads (8 waves), 40 tracks = 400 hits = 25 strips of 16 rows per block.
// Grid = 1250 blocks exactly (50000 tracks / 40), no remainder.

typedef __attribute__((ext_vector_type(8))) short short8;  // 8 bf16 (4 VGPRs) MFMA A/B frag
typedef __attribute__((ext_vector_type(4))) float f32x4;   // MFMA C/D frag

#define LATENT       256
#define HPT          10                  // hits per track
#define TPB_TRACKS   40                  // tracks per block
#define ROWS_PB      (TPB_TRACKS * HPT)  // 400 hit-rows per block
#define STRIPS_PB    (ROWS_PB / 16)      // 25 MFMA row-strips per block
#define WAVES        8
#define THREADS      (WAVES * 64)
#define W1_STRIDE    264                 // 256 + 8 bf16 pad: breaks LDS bank aliasing
#define LOG2E        1.44269504088896f

__device__ __forceinline__ short bf16_rne(float x) {
    // round-to-nearest-even fp32 -> bf16
    unsigned u = __float_as_uint(x);
    u += 0x7FFFu + ((u >> 16) & 1u);
    return (short)(u >> 16);
}

__device__ __forceinline__ float tanh_fast(float x) {
    // tanh(x) = 1 - 2/(e^{2x}+1); exp2-based, saturates correctly for |x| large
    float e = __builtin_amdgcn_exp2f(x * (2.0f * LOG2E));
    return 1.0f - 2.0f * __builtin_amdgcn_rcpf(e + 1.0f);
}

__global__ __launch_bounds__(THREADS, 2)
void softmax_pool_kernel(const float* __restrict__ h,
                         const float* __restrict__ W1,
                         const float* __restrict__ b1,
                         const float* __restrict__ w2,
                         float* __restrict__ out,
                         int n_hits, int num_tracks)
{
    __shared__ short w1t[256 * W1_STRIDE];   // W1^T bf16: [n][k], 135168 B
    __shared__ float sc_lds[ROWS_PB];        // scores then softmax weights, 1600 B

    const int tid  = threadIdx.x;
    const int wave = tid >> 6;
    const int lane = tid & 63;
    const int q    = lane >> 4;   // quad 0..3
    const int c    = lane & 15;   // low-4 lane id
    const int blk  = blockIdx.x;

    // ---------------- Phase A: W1 -> LDS as bf16, transposed [n][k] ----------------
    // Each iteration handles 2 consecutive k for one n -> packed ds_write_b32.
    for (int idx = tid; idx < 256 * 128; idx += THREADS) {
        int n = idx & 255;
        int k = (idx >> 8) << 1;
        float f0 = W1[(size_t)k * 256 + n];
        float f1 = W1[(size_t)(k + 1) * 256 + n];
        short2 p;
        p.x = bf16_rne(f0);
        p.y = bf16_rne(f1);
        *(short2*)&w1t[n * W1_STRIDE + k] = p;
    }
    __syncthreads();

    // ---------------- Phase B: scores via MFMA ----------------
    // Strip ownership: wave w owns strips {w, w+8, w+16, (w+24 if <25)}.
    const int ns = (wave == 0) ? 4 : 3;

    // A fragments: a[st][kt] holds h[row = strip*16 + c][k = kt*32 + q*8 + 0..7] as bf16
    short8 a[4][8] = {};
    #pragma unroll
    for (int st = 0; st < 4; ++st) {
        if (st < ns) {
            int strip = wave + st * 8;
            long row = (long)blk * ROWS_PB + strip * 16 + c;
            if (row >= n_hits) row = n_hits - 1;   // safe clamp (grid divides exactly anyway)
            const float* hrow = h + (size_t)row * LATENT + q * 8;
            #pragma unroll
            for (int kt = 0; kt < 8; ++kt) {
                float4 f0 = *(const float4*)(hrow + kt * 32);
                float4 f1 = *(const float4*)(hrow + kt * 32 + 4);
                short8 v;
                v[0] = bf16_rne(f0.x); v[1] = bf16_rne(f0.y);
                v[2] = bf16_rne(f0.z); v[3] = bf16_rne(f0.w);
                v[4] = bf16_rne(f1.x); v[5] = bf16_rne(f1.y);
                v[6] = bf16_rne(f1.z); v[7] = bf16_rne(f1.w);
                a[st][kt] = v;
            }
        }
    }

    f32x4 zero4 = {0.0f, 0.0f, 0.0f, 0.0f};
    f32x4 sc[4] = {zero4, zero4, zero4, zero4};   // per-strip per-row score partials

    for (int ct = 0; ct < 16; ++ct) {             // 16 column-tiles of 16
        int n = ct * 16 + c;
        const short* bbase = &w1t[n * W1_STRIDE + q * 8];
        f32x4 acc[4] = {zero4, zero4, zero4, zero4};
        #pragma unroll
        for (int kt = 0; kt < 8; ++kt) {
            short8 bf = *(const short8*)(bbase + kt * 32);   // ds_read_b128, 2-way-conflict-free
            #pragma unroll
            for (int st = 0; st < 4; ++st)
                if (st < ns)
                    acc[st] = __builtin_amdgcn_mfma_f32_16x16x32_bf16(a[st][kt], bf, acc[st], 0, 0, 0);
        }
        // acc[st][r] = u[row = strip*16 + q*4 + r][n];  fold tanh + dot(w2)
        float b1n = b1[n];
        float w2n = w2[n];
        #pragma unroll
        for (int st = 0; st < 4; ++st) {
            if (st < ns) {
                #pragma unroll
                for (int r = 0; r < 4; ++r)
                    sc[st][r] += w2n * tanh_fast(acc[st][r] + b1n);
            }
        }
    }

    // Reduce score partials across the 16 column-lanes (same quad)
    #pragma unroll
    for (int st = 0; st < 4; ++st) {
        #pragma unroll
        for (int r = 0; r < 4; ++r) {
            float v = sc[st][r];
            v += __shfl_xor(v, 1);
            v += __shfl_xor(v, 2);
            v += __shfl_xor(v, 4);
            v += __shfl_xor(v, 8);
            sc[st][r] = v;
        }
    }
    if (c == 0) {
        #pragma unroll
        for (int st = 0; st < 4; ++st) {
            if (st < ns) {
                int strip = wave + st * 8;
                float4 o;
                o.x = sc[st][0]; o.y = sc[st][1]; o.z = sc[st][2]; o.w = sc[st][3];
                *(float4*)&sc_lds[strip * 16 + q * 4] = o;   // rows strip*16 + q*4 .. +3
            }
        }
    }
    __syncthreads();

    // ---------------- Phase C: per-track softmax (scores -> weights, in place) ----------------
    if (tid < TPB_TRACKS) {
        float s[HPT];
        float m = -1e30f;
        #pragma unroll
        for (int i = 0; i < HPT; ++i) {
            s[i] = sc_lds[tid * HPT + i];
            m = fmaxf(m, s[i]);
        }
        float sum = 0.0f;
        #pragma unroll
        for (int i = 0; i < HPT; ++i) {
            s[i] = __builtin_amdgcn_exp2f((s[i] - m) * LOG2E);
            sum += s[i];
        }
        float inv = __builtin_amdgcn_rcpf(sum);
        #pragma unroll
        for (int i = 0; i < HPT; ++i)
            sc_lds[tid * HPT + i] = s[i] * inv;
    }
    __syncthreads();

    // ---------------- Phase D: weighted pooling ----------------
    // wave handles tracks {wave, wave+8, ...}: 5 tracks each. Lane owns 4 contiguous cols.
    for (int t = wave; t < TPB_TRACKS; t += WAVES) {
        int tg = blk * TPB_TRACKS + t;
        if (tg >= num_tracks) continue;
        const float* hb = h + (size_t)tg * HPT * LATENT + lane * 4;
        float4 acc = {0.0f, 0.0f, 0.0f, 0.0f};
        #pragma unroll
        for (int i = 0; i < HPT; ++i) {
            float wi = sc_lds[t * HPT + i];
            float4 v = *(const float4*)(hb + (size_t)i * LATENT);
            acc.x += wi * v.x;
            acc.y += wi * v.y;
            acc.z += wi * v.z;
            acc.w += wi * v.w;
        }
        *(float4*)(out + (size_t)tg * LATENT + lane * 4) = acc;
    }
}

extern "C" void kernel_launch(void* const* d_in, const int* in_sizes, int n_in,
                              void* d_out, int out_size, void* d_ws, size_t ws_size,
                              hipStream_t stream) {
    const float* h  = (const float*)d_in[0];
    const float* W1 = (const float*)d_in[1];
    const float* b1 = (const float*)d_in[2];
    const float* w2 = (const float*)d_in[3];
    // d_in[4] = b2 (cancels in softmax), d_in[5] = batch_indices (structure i/10 guaranteed),
    // d_in[6] = num_tracks (derived from out_size instead; device scalar unreadable on host)
    float* out = (float*)d_out;

    int n_hits     = in_sizes[0] / LATENT;    // 500000
    int num_tracks = out_size / LATENT;       // 50000
    int blocks     = (num_tracks + TPB_TRACKS - 1) / TPB_TRACKS;   // 1250

    softmax_pool_kernel<<<blocks, THREADS, 0, stream>>>(h, W1, b1, w2, out, n_hits, num_tracks);
}